// Round 1
// baseline (237.222 us; speedup 1.0000x reference)
//
#include <hip/hip_runtime.h>
#include <hip/hip_bf16.h>

#define B_ROWS 4096
#define D_DIM  256
#define N_TOT  8192            // 2B
#define E2     7.38905609893065f   // exp(2) = diagonal term of the row sum

typedef __attribute__((ext_vector_type(4))) float f32x4;
typedef __attribute__((ext_vector_type(8))) short bf16x8;   // 8 bf16 in 4 VGPRs

__device__ __forceinline__ void async_copy16(const void* gptr, void* lptr) {
    __builtin_amdgcn_global_load_lds(
        (const __attribute__((address_space(1))) unsigned int*)gptr,
        (__attribute__((address_space(3))) unsigned int*)lptr,
        16 /*bytes*/, 0 /*offset*/, 0 /*aux*/);
}

// ---------------------------------------------------------------------------
// Kernel 1: per-row L2-normalize query & pos -> bf16 Z[8192][256]; also
// accumulate sum_i dot(zq_i, zp_i) in fp32 (the "positives" sum).
// One 256-thread block per row pair; thread t owns element t (D=256).
// ---------------------------------------------------------------------------
__global__ __launch_bounds__(256) void norm_kernel(
        const float* __restrict__ q, const float* __restrict__ p,
        __hip_bfloat16* __restrict__ Z, float* __restrict__ sum_pos) {
    const int row = blockIdx.x;          // 0..4095
    const int t   = threadIdx.x;         // 0..255
    const float qv = q[row * D_DIM + t];
    const float pv = p[row * D_DIM + t];
    float a = qv * qv, b = pv * pv, c = qv * pv;
    #pragma unroll
    for (int off = 32; off > 0; off >>= 1) {
        a += __shfl_down(a, off);
        b += __shfl_down(b, off);
        c += __shfl_down(c, off);
    }
    __shared__ float red[3][4];
    const int wv = t >> 6, ln = t & 63;
    if (ln == 0) { red[0][wv] = a; red[1][wv] = b; red[2][wv] = c; }
    __syncthreads();
    const float nq  = red[0][0] + red[0][1] + red[0][2] + red[0][3];
    const float np2 = red[1][0] + red[1][1] + red[1][2] + red[1][3];
    const float qp  = red[2][0] + red[2][1] + red[2][2] + red[2][3];
    const float rq = 1.0f / fmaxf(sqrtf(nq),  1e-12f);
    const float rp = 1.0f / fmaxf(sqrtf(np2), 1e-12f);
    Z[(size_t)row * D_DIM + t]            = __float2bfloat16(qv * rq);
    Z[(size_t)(B_ROWS + row) * D_DIM + t] = __float2bfloat16(pv * rp);
    if (t == 0) atomicAdd(sum_pos, qp * rq * rp);
}

// ---------------------------------------------------------------------------
// Kernel 2: fused S = Z*Z^T with epilogue rowsum_i += sum_j exp(2*S_ij).
// 128x128 tile, 256 threads (4 waves, each a 64x64 quadrant of 4x4 MFMA
// 16x16x32 bf16 tiles). global_load_lds width-16 staging (m97 structure).
// ---------------------------------------------------------------------------
__global__ __launch_bounds__(256) void simexp_gemm(
        const __hip_bfloat16* __restrict__ Z, float* __restrict__ denom) {
    __shared__ __hip_bfloat16 As[128 * 32];   // rows of Z (output rows)
    __shared__ __hip_bfloat16 Bs[128 * 32];   // rows of Z (output cols)
    const int tid    = threadIdx.x;
    const int lane   = tid & 63;
    const int wv     = tid >> 6;      // wave id 0..3
    const int wave_m = wv >> 1;       // 0..1
    const int wave_n = wv & 1;        // 0..1
    const int rowBase = blockIdx.y * 128;
    const int colBase = blockIdx.x * 128;
    // staging: lane l loads 16B at row (l>>2), byte (l&3)*16 of a 16x64B chunk;
    // LDS dest = uniform base + lane*16 -> row-major [16][64B] exactly.
    const int srow = lane >> 2;        // 0..15
    const int scol = (lane & 3) * 8;   // bf16 element offset in K

    f32x4 acc[4][4];
    #pragma unroll
    for (int i = 0; i < 4; ++i)
        #pragma unroll
        for (int j = 0; j < 4; ++j) acc[i][j] = (f32x4){0.f, 0.f, 0.f, 0.f};

    const int m16  = lane & 15;
    const int quad = lane >> 4;

    for (int kt = 0; kt < D_DIM / 32; ++kt) {
        const int k0 = kt * 32;
        __syncthreads();   // previous iter's LDS reads done before overwrite
        #pragma unroll
        for (int c = 0; c < 2; ++c) {
            const __hip_bfloat16* gA =
                Z + (size_t)(rowBase + wv * 32 + c * 16 + srow) * D_DIM + k0 + scol;
            async_copy16(gA, (char*)As + wv * 2048 + c * 1024);
            const __hip_bfloat16* gB =
                Z + (size_t)(colBase + wv * 32 + c * 16 + srow) * D_DIM + k0 + scol;
            async_copy16(gB, (char*)Bs + wv * 2048 + c * 1024);
        }
        __syncthreads();   // drains vmcnt(0): staging complete

        bf16x8 af[4], bfr[4];
        #pragma unroll
        for (int mi = 0; mi < 4; ++mi)
            af[mi] = *(const bf16x8*)&As[(wave_m * 64 + mi * 16 + m16) * 32 + quad * 8];
        #pragma unroll
        for (int ni = 0; ni < 4; ++ni)
            bfr[ni] = *(const bf16x8*)&Bs[(wave_n * 64 + ni * 16 + m16) * 32 + quad * 8];
        #pragma unroll
        for (int mi = 0; mi < 4; ++mi)
            #pragma unroll
            for (int ni = 0; ni < 4; ++ni)
                acc[mi][ni] = __builtin_amdgcn_mfma_f32_16x16x32_bf16(
                    af[mi], bfr[ni], acc[mi][ni], 0, 0, 0);
    }

    // Epilogue: per-lane partial rowsums of exp(2*s), then reduce across the
    // 16 lanes (same quad, different column) and atomicAdd per row.
    // C/D layout: col = lane&15, row = quad*4 + reg  [m89-verified].
    float ps[4][4];
    #pragma unroll
    for (int mi = 0; mi < 4; ++mi)
        #pragma unroll
        for (int r = 0; r < 4; ++r) {
            float s = 0.f;
            #pragma unroll
            for (int ni = 0; ni < 4; ++ni) s += __expf(2.0f * acc[mi][ni][r]);
            ps[mi][r] = s;
        }
    #pragma unroll
    for (int off = 1; off < 16; off <<= 1)
        #pragma unroll
        for (int mi = 0; mi < 4; ++mi)
            #pragma unroll
            for (int r = 0; r < 4; ++r)
                ps[mi][r] += __shfl_xor(ps[mi][r], off, 64);
    if (m16 == 0) {
        #pragma unroll
        for (int mi = 0; mi < 4; ++mi)
            #pragma unroll
            for (int r = 0; r < 4; ++r)
                atomicAdd(&denom[rowBase + wave_m * 64 + mi * 16 + quad * 4 + r],
                          ps[mi][r]);
    }
}

// ---------------------------------------------------------------------------
// Kernel 3: loss = (sum_i log(denom_i - e^2) - 4*sum_pos) / 8192
// ---------------------------------------------------------------------------
__global__ __launch_bounds__(256) void finalize_kernel(
        const float* __restrict__ denom, const float* __restrict__ sum_pos,
        float* __restrict__ out) {
    const int t = threadIdx.x;
    float s = 0.f;
    for (int i = t; i < N_TOT; i += 256) s += logf(denom[i] - E2);
    #pragma unroll
    for (int off = 32; off > 0; off >>= 1) s += __shfl_down(s, off);
    __shared__ float red[4];
    if ((t & 63) == 0) red[t >> 6] = s;
    __syncthreads();
    if (t == 0)
        out[0] = (red[0] + red[1] + red[2] + red[3] - 4.0f * sum_pos[0])
                 / (float)N_TOT;
}

extern "C" void kernel_launch(void* const* d_in, const int* in_sizes, int n_in,
                              void* d_out, int out_size, void* d_ws, size_t ws_size,
                              hipStream_t stream) {
    const float* q = (const float*)d_in[0];
    const float* p = (const float*)d_in[1];
    // d_in[2] (neg) is normalized in the original but never used in the loss.
    float* out = (float*)d_out;

    // Workspace layout: Z bf16 [8192*256] (4 MiB) | denom f32 [8192] | sum_pos f32
    __hip_bfloat16* Z = (__hip_bfloat16*)d_ws;
    float* denom   = (float*)((char*)d_ws + (size_t)N_TOT * D_DIM * sizeof(__hip_bfloat16));
    float* sum_pos = denom + N_TOT;

    hipMemsetAsync(denom, 0, (N_TOT + 1) * sizeof(float), stream);
    hipLaunchKernelGGL(norm_kernel, dim3(B_ROWS), dim3(256), 0, stream,
                       q, p, Z, sum_pos);
    hipLaunchKernelGGL(simexp_gemm, dim3(N_TOT / 128, N_TOT / 128), dim3(256),
                       0, stream, Z, denom);
    hipLaunchKernelGGL(finalize_kernel, dim3(1), dim3(256), 0, stream,
                       denom, sum_pos, out);
}

// Round 2
// 148.351 us; speedup vs baseline: 1.5991x; 1.5991x over previous
//
#include <hip/hip_runtime.h>
#include <hip/hip_bf16.h>
#include <math.h>

#define B_ROWS 4096
#define D_DIM  256
#define N_TOT  8192            // 2B
#define E2     7.38905609893065f   // exp(2) = diagonal term of the row sum
#define NTILE  64              // 8192 / 128
#define NBLK   (NTILE * (NTILE + 1) / 2)   // 2080 upper-triangle tile pairs

typedef __attribute__((ext_vector_type(4))) float f32x4;
typedef __attribute__((ext_vector_type(8))) short bf16x8;   // 8 bf16 in 4 VGPRs

__device__ __forceinline__ void async_copy16(const void* gptr, void* lptr) {
    __builtin_amdgcn_global_load_lds(
        (const __attribute__((address_space(1))) unsigned int*)gptr,
        (__attribute__((address_space(3))) unsigned int*)lptr,
        16 /*bytes*/, 0 /*offset*/, 0 /*aux*/);
}

// ---------------------------------------------------------------------------
// Kernel 1: per-row L2-normalize query & pos -> bf16 Z[8192][256]; write the
// per-row positive dot (zq_i . zp_i) to pospart[row] (NO single-address
// atomic -- the 4096 serialized atomics were a prime suspect for ~100us).
// ---------------------------------------------------------------------------
__global__ __launch_bounds__(256) void norm_kernel(
        const float* __restrict__ q, const float* __restrict__ p,
        __hip_bfloat16* __restrict__ Z, float* __restrict__ pospart) {
    const int row = blockIdx.x;          // 0..4095
    const int t   = threadIdx.x;         // 0..255
    const float qv = q[row * D_DIM + t];
    const float pv = p[row * D_DIM + t];
    float a = qv * qv, b = pv * pv, c = qv * pv;
    #pragma unroll
    for (int off = 32; off > 0; off >>= 1) {
        a += __shfl_down(a, off);
        b += __shfl_down(b, off);
        c += __shfl_down(c, off);
    }
    __shared__ float red[3][4];
    const int wv = t >> 6, ln = t & 63;
    if (ln == 0) { red[0][wv] = a; red[1][wv] = b; red[2][wv] = c; }
    __syncthreads();
    const float nq  = red[0][0] + red[0][1] + red[0][2] + red[0][3];
    const float np2 = red[1][0] + red[1][1] + red[1][2] + red[1][3];
    const float qp  = red[2][0] + red[2][1] + red[2][2] + red[2][3];
    const float rq = 1.0f / fmaxf(sqrtf(nq),  1e-12f);
    const float rp = 1.0f / fmaxf(sqrtf(np2), 1e-12f);
    Z[(size_t)row * D_DIM + t]            = __float2bfloat16(qv * rq);
    Z[(size_t)(B_ROWS + row) * D_DIM + t] = __float2bfloat16(pv * rp);
    if (t == 0) pospart[row] = qp * rq * rp;
}

// ---------------------------------------------------------------------------
// Kernel 2: fused S = Z*Z^T, upper-triangle tile pairs only (symmetry).
// Whole K=256 staged once into LDS (64KB + 64KB), ONE barrier, then 8 pure
// LDS->MFMA k-steps with no syncs. XOR swizzle (applied on the global source
// side, since global_load_lds dst is base+lane*16) keeps ds_read_b128 at
// <=2-way bank aliasing (free).
// Off-diagonal tiles add exp-rowsums to both row-rows and col-rows of denom.
// ---------------------------------------------------------------------------
__global__ __launch_bounds__(256) void simexp_gemm(
        const __hip_bfloat16* __restrict__ Z, float* __restrict__ denom) {
    __shared__ __hip_bfloat16 As[128 * 256];   // 64 KB, row stride 512B
    __shared__ __hip_bfloat16 Bs[128 * 256];   // 64 KB
    const int tid    = threadIdx.x;
    const int lane   = tid & 63;
    const int wv     = tid >> 6;      // wave id 0..3
    const int wave_m = wv >> 1;       // 0..1  (row half)
    const int wave_n = wv & 1;        // 0..1  (col half)
    const int m16    = lane & 15;
    const int quad   = lane >> 4;

    // --- triangular decode: bid -> (bi <= bj) ---
    const int bid = blockIdx.x;
    int bi = (int)((129.0 - sqrt(129.0 * 129.0 - 8.0 * (double)bid)) * 0.5);
    while (bi > 0 && (bi * NTILE - bi * (bi - 1) / 2) > bid) --bi;
    while (((bi + 1) * NTILE - (bi + 1) * bi / 2) <= bid) ++bi;
    const int bj = bi + (bid - (bi * NTILE - bi * (bi - 1) / 2));
    const int rowBase = bi * 128;
    const int colBase = bj * 128;

    // --- stage both full 128x256 tiles, one barrier ---
    // slot = p*256 + wv*64 + lane ; row = slot>>5 ; stored 16B-chunk = lane&31.
    // LDS chunk s holds global chunk s ^ (row&7)  (xor is an involution).
    const int stc = lane & 31;
    #pragma unroll
    for (int p = 0; p < 16; ++p) {
        const int row = p * 8 + wv * 2 + (lane >> 5);
        const int g   = stc ^ (row & 7);           // global 16B-chunk index
        const __hip_bfloat16* srcA = Z + (size_t)(rowBase + row) * D_DIM + g * 8;
        const __hip_bfloat16* srcB = Z + (size_t)(colBase + row) * D_DIM + g * 8;
        async_copy16(srcA, (char*)As + p * 4096 + wv * 1024);
        async_copy16(srcB, (char*)Bs + p * 4096 + wv * 1024);
    }
    __syncthreads();   // single barrier: drains vmcnt, staging complete

    f32x4 acc[4][4];
    #pragma unroll
    for (int i = 0; i < 4; ++i)
        #pragma unroll
        for (int j = 0; j < 4; ++j) acc[i][j] = (f32x4){0.f, 0.f, 0.f, 0.f};

    #pragma unroll
    for (int kt = 0; kt < 8; ++kt) {
        bf16x8 af[4], bfr[4];
        // row&7 == m16&7 (row bases are multiples of 16)
        const int sw = (kt * 4 + quad) ^ (m16 & 7);  // swizzled chunk
        #pragma unroll
        for (int mi = 0; mi < 4; ++mi) {
            const int r = wave_m * 64 + mi * 16 + m16;
            af[mi] = *(const bf16x8*)((const char*)As + r * 512 + sw * 16);
        }
        #pragma unroll
        for (int ni = 0; ni < 4; ++ni) {
            const int r = wave_n * 64 + ni * 16 + m16;
            bfr[ni] = *(const bf16x8*)((const char*)Bs + r * 512 + sw * 16);
        }
        #pragma unroll
        for (int mi = 0; mi < 4; ++mi)
            #pragma unroll
            for (int ni = 0; ni < 4; ++ni)
                acc[mi][ni] = __builtin_amdgcn_mfma_f32_16x16x32_bf16(
                    af[mi], bfr[ni], acc[mi][ni], 0, 0, 0);
    }

    // --- epilogue: exp(2s) once; accumulate row partials and col partials ---
    // C/D layout: col = lane&15, row = quad*4 + reg  [m89-verified].
    float cs[4] = {0.f, 0.f, 0.f, 0.f};
    float rs[4][4];
    #pragma unroll
    for (int mi = 0; mi < 4; ++mi)
        #pragma unroll
        for (int r = 0; r < 4; ++r) {
            float s = 0.f;
            #pragma unroll
            for (int ni = 0; ni < 4; ++ni) {
                const float e = __expf(2.0f * acc[mi][ni][r]);
                s += e;
                cs[ni] += e;
            }
            rs[mi][r] = s;
        }
    // row sums: reduce across the 16 columns (lanes sharing a quad)
    #pragma unroll
    for (int off = 1; off < 16; off <<= 1)
        #pragma unroll
        for (int mi = 0; mi < 4; ++mi)
            #pragma unroll
            for (int r = 0; r < 4; ++r)
                rs[mi][r] += __shfl_xor(rs[mi][r], off, 64);
    if (m16 == 0) {
        #pragma unroll
        for (int mi = 0; mi < 4; ++mi)
            #pragma unroll
            for (int r = 0; r < 4; ++r)
                atomicAdd(&denom[rowBase + wave_m * 64 + mi * 16 + quad * 4 + r],
                          rs[mi][r]);
    }
    // col sums: reduce across the 4 quads (rows) -> symmetric contribution
    if (bi != bj) {
        #pragma unroll
        for (int off = 16; off < 64; off <<= 1)
            #pragma unroll
            for (int ni = 0; ni < 4; ++ni)
                cs[ni] += __shfl_xor(cs[ni], off, 64);
        if (lane < 16) {
            #pragma unroll
            for (int ni = 0; ni < 4; ++ni)
                atomicAdd(&denom[colBase + wave_n * 64 + ni * 16 + m16], cs[ni]);
        }
    }
}

// ---------------------------------------------------------------------------
// Kernel 3: loss = (sum_i log(denom_i - e^2) - 4*sum_i pospart_i) / 8192
// ---------------------------------------------------------------------------
__global__ __launch_bounds__(256) void finalize_kernel(
        const float* __restrict__ denom, const float* __restrict__ pospart,
        float* __restrict__ out) {
    const int t = threadIdx.x;
    float s = 0.f;
    for (int i = t; i < N_TOT; i += 256) s += logf(denom[i] - E2);
    float pp = 0.f;
    for (int i = t; i < B_ROWS; i += 256) pp += pospart[i];
    s -= 4.0f * pp;
    #pragma unroll
    for (int off = 32; off > 0; off >>= 1) s += __shfl_down(s, off);
    __shared__ float red[4];
    if ((t & 63) == 0) red[t >> 6] = s;
    __syncthreads();
    if (t == 0)
        out[0] = (red[0] + red[1] + red[2] + red[3]) / (float)N_TOT;
}

extern "C" void kernel_launch(void* const* d_in, const int* in_sizes, int n_in,
                              void* d_out, int out_size, void* d_ws, size_t ws_size,
                              hipStream_t stream) {
    const float* q = (const float*)d_in[0];
    const float* p = (const float*)d_in[1];
    // d_in[2] (neg) is normalized in the original but never used in the loss.
    float* out = (float*)d_out;

    // Workspace: Z bf16 [8192*256] (4 MiB) | denom f32 [8192] | pospart f32 [4096]
    __hip_bfloat16* Z = (__hip_bfloat16*)d_ws;
    float* denom   = (float*)((char*)d_ws + (size_t)N_TOT * D_DIM * sizeof(__hip_bfloat16));
    float* pospart = denom + N_TOT;

    hipMemsetAsync(denom, 0, N_TOT * sizeof(float), stream);
    hipLaunchKernelGGL(norm_kernel, dim3(B_ROWS), dim3(256), 0, stream,
                       q, p, Z, pospart);
    hipLaunchKernelGGL(simexp_gemm, dim3(NBLK), dim3(256), 0, stream, Z, denom);
    hipLaunchKernelGGL(finalize_kernel, dim3(1), dim3(256), 0, stream,
                       denom, pospart, out);
}

// Round 3
// 121.293 us; speedup vs baseline: 1.9558x; 1.2231x over previous
//
#include <hip/hip_runtime.h>
#include <hip/hip_bf16.h>
#include <math.h>

#define B_ROWS 4096
#define D_DIM  256
#define N_TOT  8192            // 2B
#define E2     7.38905609893065f   // exp(2) = diagonal term of the row sum
#define NTILE  64              // 8192 / 128
#define NBLK   (NTILE * (NTILE + 1) / 2)   // 2080 upper-triangle tile pairs

typedef __attribute__((ext_vector_type(4))) float f32x4;
typedef __attribute__((ext_vector_type(8))) short bf16x8;   // 8 bf16 in 4 VGPRs

__device__ __forceinline__ void async_copy16(const void* gptr, void* lptr) {
    // NOTE: lptr is the WAVE-UNIFORM base; HW scatters lane*16 itself.
    __builtin_amdgcn_global_load_lds(
        (const __attribute__((address_space(1))) unsigned int*)gptr,
        (__attribute__((address_space(3))) unsigned int*)lptr,
        16 /*bytes*/, 0 /*offset*/, 0 /*aux*/);
}

// ---------------------------------------------------------------------------
// Kernel 1: per-row L2-normalize query & pos -> bf16 Z[8192][256]; per-row
// positive dot to pospart[row]. Blocks 0..31 also zero denom[8192] (replaces
// the separate memset dispatch; kernel-boundary ordering makes this safe).
// ---------------------------------------------------------------------------
__global__ __launch_bounds__(256) void norm_kernel(
        const float* __restrict__ q, const float* __restrict__ p,
        __hip_bfloat16* __restrict__ Z, float* __restrict__ pospart,
        float* __restrict__ denom) {
    const int row = blockIdx.x;          // 0..4095
    const int t   = threadIdx.x;         // 0..255
    if (row < 32) denom[row * 256 + t] = 0.0f;
    const float qv = q[row * D_DIM + t];
    const float pv = p[row * D_DIM + t];
    float a = qv * qv, b = pv * pv, c = qv * pv;
    #pragma unroll
    for (int off = 32; off > 0; off >>= 1) {
        a += __shfl_down(a, off);
        b += __shfl_down(b, off);
        c += __shfl_down(c, off);
    }
    __shared__ float red[3][4];
    const int wv = t >> 6, ln = t & 63;
    if (ln == 0) { red[0][wv] = a; red[1][wv] = b; red[2][wv] = c; }
    __syncthreads();
    const float nq  = red[0][0] + red[0][1] + red[0][2] + red[0][3];
    const float np2 = red[1][0] + red[1][1] + red[1][2] + red[1][3];
    const float qp  = red[2][0] + red[2][1] + red[2][2] + red[2][3];
    const float rq = 1.0f / fmaxf(sqrtf(nq),  1e-12f);
    const float rp = 1.0f / fmaxf(sqrtf(np2), 1e-12f);
    Z[(size_t)row * D_DIM + t]            = __float2bfloat16(qv * rq);
    Z[(size_t)(B_ROWS + row) * D_DIM + t] = __float2bfloat16(pv * rp);
    if (t == 0) pospart[row] = qp * rq * rp;
}

// ---------------------------------------------------------------------------
// Kernel 2: fused S = Z*Z^T, upper-triangle tile pairs (symmetry), with
// epilogue rowsum += sum_j exp(2*S). 128x128 tile, BK=64 (4 K-iters), LDS
// 16+16 KB single-buffered -> 3 blocks/CU (12 waves/CU, m97 regime): barrier
// drains in one block are covered by the other blocks' MFMA waves.
// XOR swizzle on the global source side keeps ds_read_b128 at the balanced
// bank floor. launch_bounds(256,3) caps VGPR at ~170 (natural ~135).
// ---------------------------------------------------------------------------
__global__ __launch_bounds__(256, 3) void simexp_gemm(
        const __hip_bfloat16* __restrict__ Z, float* __restrict__ denom) {
    __shared__ __hip_bfloat16 As[128 * 64];   // 16 KB, row stride 128 B
    __shared__ __hip_bfloat16 Bs[128 * 64];   // 16 KB
    const int tid    = threadIdx.x;
    const int lane   = tid & 63;
    const int wv     = tid >> 6;      // wave id 0..3
    const int wave_m = wv >> 1;       // 0..1  (row half)
    const int wave_n = wv & 1;        // 0..1  (col half)
    const int m16    = lane & 15;
    const int quad   = lane >> 4;

    // --- triangular decode: bid -> (bi <= bj) ---
    const int bid = blockIdx.x;
    int bi = (int)((129.0 - sqrt(129.0 * 129.0 - 8.0 * (double)bid)) * 0.5);
    while (bi > 0 && (bi * NTILE - bi * (bi - 1) / 2) > bid) --bi;
    while (((bi + 1) * NTILE - (bi + 1) * bi / 2) <= bid) ++bi;
    const int bj = bi + (bid - (bi * NTILE - bi * (bi - 1) / 2));
    const int rowBase = bi * 128;
    const int colBase = bj * 128;

    f32x4 acc[4][4];
    #pragma unroll
    for (int i = 0; i < 4; ++i)
        #pragma unroll
        for (int j = 0; j < 4; ++j) acc[i][j] = (f32x4){0.f, 0.f, 0.f, 0.f};

    // staging geometry: one instr = 64 lanes x 16B = 8 rows of 128B.
    // lane l -> local row (l>>3), chunk slot (l&7); LDS chunk c of row r
    // holds global chunk c ^ (r&7) (xor involution).
    const int lrow = lane >> 3;        // 0..7 within an 8-row group
    const int lchk = lane & 7;         // 16B chunk slot

    for (int kt = 0; kt < 4; ++kt) {
        const int k0 = kt * 64;
        __syncthreads();   // previous iter's LDS reads done before overwrite
        #pragma unroll
        for (int pp = 0; pp < 4; ++pp) {
            const int r = wv * 32 + pp * 8 + lrow;      // local row 0..127
            const int g = lchk ^ (r & 7);               // swizzled global chunk
            const __hip_bfloat16* srcA =
                Z + (size_t)(rowBase + r) * D_DIM + k0 + g * 8;
            const __hip_bfloat16* srcB =
                Z + (size_t)(colBase + r) * D_DIM + k0 + g * 8;
            async_copy16(srcA, (char*)As + (wv * 32 + pp * 8) * 128);
            async_copy16(srcB, (char*)Bs + (wv * 32 + pp * 8) * 128);
        }
        __syncthreads();   // drains vmcnt: staging complete

        #pragma unroll
        for (int kt2 = 0; kt2 < 2; ++kt2) {
            const int sw = (kt2 * 4 + quad) ^ (m16 & 7);  // swizzled chunk
            bf16x8 af[4], bfr[4];
            #pragma unroll
            for (int mi = 0; mi < 4; ++mi) {
                const int r = wave_m * 64 + mi * 16 + m16;
                af[mi] = *(const bf16x8*)((const char*)As + r * 128 + sw * 16);
            }
            #pragma unroll
            for (int ni = 0; ni < 4; ++ni) {
                const int r = wave_n * 64 + ni * 16 + m16;
                bfr[ni] = *(const bf16x8*)((const char*)Bs + r * 128 + sw * 16);
            }
            #pragma unroll
            for (int mi = 0; mi < 4; ++mi)
                #pragma unroll
                for (int ni = 0; ni < 4; ++ni)
                    acc[mi][ni] = __builtin_amdgcn_mfma_f32_16x16x32_bf16(
                        af[mi], bfr[ni], acc[mi][ni], 0, 0, 0);
        }
    }

    // --- epilogue: exp(2s) once; accumulate row partials and col partials ---
    // C/D layout: col = lane&15, row = quad*4 + reg  [m89-verified].
    float cs[4] = {0.f, 0.f, 0.f, 0.f};
    float rs[4][4];
    #pragma unroll
    for (int mi = 0; mi < 4; ++mi)
        #pragma unroll
        for (int r = 0; r < 4; ++r) {
            float s = 0.f;
            #pragma unroll
            for (int ni = 0; ni < 4; ++ni) {
                const float e = __expf(2.0f * acc[mi][ni][r]);
                s += e;
                cs[ni] += e;
            }
            rs[mi][r] = s;
        }
    // row sums: reduce across the 16 columns (lanes sharing a quad)
    #pragma unroll
    for (int off = 1; off < 16; off <<= 1)
        #pragma unroll
        for (int mi = 0; mi < 4; ++mi)
            #pragma unroll
            for (int r = 0; r < 4; ++r)
                rs[mi][r] += __shfl_xor(rs[mi][r], off, 64);
    if (m16 == 0) {
        #pragma unroll
        for (int mi = 0; mi < 4; ++mi)
            #pragma unroll
            for (int r = 0; r < 4; ++r)
                atomicAdd(&denom[rowBase + wave_m * 64 + mi * 16 + quad * 4 + r],
                          rs[mi][r]);
    }
    // col sums: reduce across the 4 quads (rows) -> symmetric contribution
    if (bi != bj) {
        #pragma unroll
        for (int off = 16; off < 64; off <<= 1)
            #pragma unroll
            for (int ni = 0; ni < 4; ++ni)
                cs[ni] += __shfl_xor(cs[ni], off, 64);
        if (lane < 16) {
            #pragma unroll
            for (int ni = 0; ni < 4; ++ni)
                atomicAdd(&denom[colBase + wave_n * 64 + ni * 16 + m16], cs[ni]);
        }
    }
}

// ---------------------------------------------------------------------------
// Kernel 3: loss = (sum_i log(denom_i - e^2) - 4*sum_i pospart_i) / 8192
// ---------------------------------------------------------------------------
__global__ __launch_bounds__(256) void finalize_kernel(
        const float* __restrict__ denom, const float* __restrict__ pospart,
        float* __restrict__ out) {
    const int t = threadIdx.x;
    float s = 0.f;
    for (int i = t; i < N_TOT; i += 256) s += logf(denom[i] - E2);
    float pp = 0.f;
    for (int i = t; i < B_ROWS; i += 256) pp += pospart[i];
    s -= 4.0f * pp;
    #pragma unroll
    for (int off = 32; off > 0; off >>= 1) s += __shfl_down(s, off);
    __shared__ float red[4];
    if ((t & 63) == 0) red[t >> 6] = s;
    __syncthreads();
    if (t == 0)
        out[0] = (red[0] + red[1] + red[2] + red[3]) / (float)N_TOT;
}

extern "C" void kernel_launch(void* const* d_in, const int* in_sizes, int n_in,
                              void* d_out, int out_size, void* d_ws, size_t ws_size,
                              hipStream_t stream) {
    const float* q = (const float*)d_in[0];
    const float* p = (const float*)d_in[1];
    // d_in[2] (neg) is normalized in the original but never used in the loss.
    float* out = (float*)d_out;

    // Workspace: Z bf16 [8192*256] (4 MiB) | denom f32 [8192] | pospart f32 [4096]
    __hip_bfloat16* Z = (__hip_bfloat16*)d_ws;
    float* denom   = (float*)((char*)d_ws + (size_t)N_TOT * D_DIM * sizeof(__hip_bfloat16));
    float* pospart = denom + N_TOT;

    hipLaunchKernelGGL(norm_kernel, dim3(B_ROWS), dim3(256), 0, stream,
                       q, p, Z, pospart, denom);
    hipLaunchKernelGGL(simexp_gemm, dim3(NBLK), dim3(256), 0, stream, Z, denom);
    hipLaunchKernelGGL(finalize_kernel, dim3(1), dim3(256), 0, stream,
                       denom, pospart, out);
}